// Round 8
// baseline (753.088 us; speedup 1.0000x reference)
//
#include <hip/hip_runtime.h>
#include <hip/hip_bf16.h>

#define BATCH 32
#define SEQ   2048
#define HID   1024
#define M_TOT (BATCH*SEQ)
#define NG    32          // K groups of 32 (each does xh*wh, xh*wl, xl*wh)

typedef __attribute__((ext_vector_type(8))) short          bf16x8;
typedef __attribute__((ext_vector_type(8))) unsigned short us8;
typedef __attribute__((ext_vector_type(4))) float          f32x4;
typedef __attribute__((ext_vector_type(4))) unsigned       u32x4;

__device__ __forceinline__ unsigned short f2bf_rn(float x) {
    unsigned u = __float_as_uint(x);
    return (unsigned short)((u + 0x7fffu + ((u >> 16) & 1u)) >> 16);
}
__device__ __forceinline__ float bf2f(unsigned short h) {
    return __uint_as_float(((unsigned)h) << 16);
}
// packed f32x2 -> bf16x2 (lo <- s0, hi <- s1), RTNE on gfx950
__device__ __forceinline__ unsigned cvt_pk_bf16(float s0, float s1) {
    unsigned r;
    asm("v_cvt_pk_bf16_f32 %0, %1, %2" : "=v"(r) : "v"(s0), "v"(s1));
    return r;
}

using as1_cv = const __attribute__((address_space(1))) void;
using as3_v  = __attribute__((address_space(3))) void;
__device__ __forceinline__ void gload16(const void* g, char* s) {
    __builtin_amdgcn_global_load_lds((as1_cv*)g, (as3_v*)s, 16, 0, 0);
}

#define FENCE() asm volatile("" ::: "memory")

// ---------------- kernel 0: W f32 -> bf16 hi/lo  w2 = [o][ wh(1024) | wl(1024) ] --
__global__ __launch_bounds__(256) void k_convW(const float* __restrict__ W,
                                               unsigned short* __restrict__ w2) {
    const int i8 = (blockIdx.x * 256 + threadIdx.x) * 8;
    const int o = i8 >> 10, h = i8 & 1023;
    float4 w0 = *(const float4*)(W + i8);
    float4 w1 = *(const float4*)(W + i8 + 4);
    float xs[8] = {w0.x, w0.y, w0.z, w0.w, w1.x, w1.y, w1.z, w1.w};
    us8 hv{}, lv{};
#pragma unroll
    for (int t = 0; t < 8; t++) {
        unsigned short xh = f2bf_rn(xs[t]);
        hv[t] = (unsigned short)xh;
        lv[t] = (unsigned short)f2bf_rn(xs[t] - bf2f(xh));
    }
    *(us8*)(w2 + (size_t)o * 2048 + h)        = hv;
    *(us8*)(w2 + (size_t)o * 2048 + 1024 + h) = lv;
}

// ------ kernel 1: fused (enc+hidden) @ W^T -> tanh -> dot(v) -> pscore16 ------
// A path is REGISTER-ONLY: each wave's MFMA A-fragment (row wr*128+i*16+fr,
// k = g*8..+7) is a private 32B enc segment -> load f32, add hidden
// (LDS broadcast), cvt to bf16 hi/lo frags in regs. No A LDS round-trip.
// LDS (68 KB): B 2 slots x [wh|wl] x [256 rows][64 B] = 64 KB (XOR-swizzled,
// 16B-chunk c of row r at c ^ ((r>>1)&3)); hidL 4 KB f32 at 65536.
// Sync: ONE barrier per group, s_waitcnt vmcnt(0)+lgkmcnt(0) (drained DMAs
// are a full group old -> free). B double-buffered on parity, staged 1 ahead.
__global__ __launch_bounds__(512, 2) void k_gemm_scores(
    const float* __restrict__ enc,
    const float* __restrict__ hidden,
    const unsigned short* __restrict__ w2,
    const float* __restrict__ b_attn,
    const float* __restrict__ v,
    float* __restrict__ pscore16)
{
    extern __shared__ char smem[];
    float* hidL = (float*)(smem + 65536);

    const int tid  = threadIdx.x;
    const int lane = tid & 63, wid = tid >> 6;
    const int wr = wid >> 2, wc = wid & 3;
    const int fr = lane & 15, g = lane >> 4;
    const int gxr = (fr >> 1) & 3;          // fragment-read XOR (lane-constant)
    const int gsw = (g ^ gxr) * 16;         // swizzled chunk byte offset for reads

    const int bid  = blockIdx.x;
    const int swz  = (bid & 7) * 128 + (bid >> 3);   // XCD-chunk swizzle (bijective, nwg=1024)
    const int mbase = (swz >> 2) * 256;
    const int nbase = (swz & 3) * 256;
    const int bidx  = mbase >> 11;                   // batch (BM=256 divides SEQ)

    // per-lane A base: enc row (mbase + wr*128 + fr), k offset g*8
    const float* encBase = enc + (size_t)(mbase + wr * 128 + fr) * HID + g * 8;

    // B gload mapping: dest linear (lane*16); source chunk pre-swizzled
    const int brow  = wid * 16 + (lane >> 2);
    const int bsx8  = ((lane & 3) ^ ((lane >> 3) & 3)) * 8;

    // hidden row -> LDS (1024 f32)
    *(float2*)(hidL + tid * 2) = *(const float2*)(hidden + (size_t)bidx * HID + tid * 2);

    f32x4 acc[8][4];
#pragma unroll
    for (int i = 0; i < 8; i++)
#pragma unroll
        for (int j = 0; j < 4; j++) acc[i][j] = (f32x4)0.f;

    bf16x8 FH[8], FL[8], bh[4], bl[4];

    // direct enc->frag conversion for set i of group Gn (writes FH[i], FL[i])
    auto convSet = [&](int i, int Gn, const float* hv) {
        const float* ep = encBase + (size_t)(i * 16) * HID + Gn * 32;
        float4 e0 = *(const float4*)ep;
        float4 e1 = *(const float4*)(ep + 4);
        float x0 = e0.x + hv[0], x1 = e0.y + hv[1];
        float x2 = e0.z + hv[2], x3 = e0.w + hv[3];
        float x4 = e1.x + hv[4], x5 = e1.y + hv[5];
        float x6 = e1.z + hv[6], x7 = e1.w + hv[7];
        unsigned h01 = cvt_pk_bf16(x0, x1);
        unsigned h23 = cvt_pk_bf16(x2, x3);
        unsigned h45 = cvt_pk_bf16(x4, x5);
        unsigned h67 = cvt_pk_bf16(x6, x7);
        unsigned l01 = cvt_pk_bf16(x0 - __uint_as_float(h01 << 16),
                                   x1 - __uint_as_float(h01 & 0xffff0000u));
        unsigned l23 = cvt_pk_bf16(x2 - __uint_as_float(h23 << 16),
                                   x3 - __uint_as_float(h23 & 0xffff0000u));
        unsigned l45 = cvt_pk_bf16(x4 - __uint_as_float(h45 << 16),
                                   x5 - __uint_as_float(h45 & 0xffff0000u));
        unsigned l67 = cvt_pk_bf16(x6 - __uint_as_float(h67 << 16),
                                   x7 - __uint_as_float(h67 & 0xffff0000u));
        union { u32x4 u; bf16x8 b; } H, L;
        H.u[0] = h01; H.u[1] = h23; H.u[2] = h45; H.u[3] = h67;
        L.u[0] = l01; L.u[1] = l23; L.u[2] = l45; L.u[3] = l67;
        FH[i] = H.b;
        FL[i] = L.b;
    };
    auto stageB = [&](int G2, int part) {   // part: 0=wh, 1=wl ; 2 gloads
        const unsigned short* s0 = w2 + (size_t)(nbase + brow) * 2048 + part * 1024 + G2 * 32 + bsx8;
        char* d0 = smem + (G2 & 1) * 32768 + part * 16384 + wid * 1024;
        gload16(s0, d0);
        gload16(s0 + (size_t)128 * 2048, d0 + 8192);
    };
    auto rdB = [&](int slot, int part, int j) -> bf16x8 {
        return *(const bf16x8*)(smem + slot * 32768 + part * 16384 +
                                (wc * 64 + j * 16 + fr) * 64 + gsw);
    };

    // ---- prologue: hidL; B(0) DMA; conv frags for G=0 ----
    stageB(0, 0); stageB(0, 1);
    asm volatile("s_waitcnt lgkmcnt(0)" ::: "memory");   // hidL ds_write done
    __builtin_amdgcn_s_barrier(); FENCE();
    {
        float hv[8];
        *(float4*)&hv[0] = *(const float4*)(hidL + g * 8);
        *(float4*)&hv[4] = *(const float4*)(hidL + g * 8 + 4);
#pragma unroll
        for (int i = 0; i < 8; i++) convSet(i, 0, hv);
    }

    for (int G = 0; G < NG; ++G) {
        const int slot = G & 1;
        // ---- group top: B(G) DMA done (issued a full group ago) ----
        asm volatile("s_waitcnt vmcnt(0) lgkmcnt(0)" ::: "memory");
        __builtin_amdgcn_s_barrier(); FENCE();

        if (G + 1 < NG) { stageB(G + 1, 0); stageB(G + 1, 1); } // -> slot^1
#pragma unroll
        for (int j = 0; j < 4; j++) bh[j] = rdB(slot, 0, j);
#pragma unroll
        for (int j = 0; j < 4; j++) bl[j] = rdB(slot, 1, j);

        // ---- 64 MFMA: xh * {wh, wl} ----
        __builtin_amdgcn_s_setprio(1);
#pragma unroll
        for (int i = 0; i < 8; i++)
#pragma unroll
            for (int j = 0; j < 4; j++)
                acc[i][j] = __builtin_amdgcn_mfma_f32_16x16x32_bf16(FH[i], bh[j], acc[i][j], 0, 0, 0);
#pragma unroll
        for (int i = 0; i < 8; i++)
#pragma unroll
            for (int j = 0; j < 4; j++)
                acc[i][j] = __builtin_amdgcn_mfma_f32_16x16x32_bf16(FH[i], bl[j], acc[i][j], 0, 0, 0);
        __builtin_amdgcn_s_setprio(0);

        // hid values for next group's conv (broadcast read, 16 lanes/addr)
        float hv[8];
        if (G + 1 < NG) {
            *(float4*)&hv[0] = *(const float4*)(hidL + (G + 1) * 32 + g * 8);
            *(float4*)&hv[4] = *(const float4*)(hidL + (G + 1) * 32 + g * 8 + 4);
        }

        // ---- 32 MFMA xl*wh, interleaved per-set with conv of group G+1 ----
        // (FH[i]/FL[i] of G are dead exactly when convSet(i,G+1) rewrites them)
#pragma unroll
        for (int i = 0; i < 8; i++) {
            __builtin_amdgcn_s_setprio(1);
#pragma unroll
            for (int j = 0; j < 4; j++)
                acc[i][j] = __builtin_amdgcn_mfma_f32_16x16x32_bf16(FL[i], bh[j], acc[i][j], 0, 0, 0);
            __builtin_amdgcn_s_setprio(0);
            if (G + 1 < NG) convSet(i, G + 1, hv);
        }
    }

    // ---- epilogue: tanh(e+b)*v, reduce over cols, write 1 plane per (nblk,wc) ----
    float rs[8][4];
#pragma unroll
    for (int i = 0; i < 8; i++)
#pragma unroll
        for (int r = 0; r < 4; r++) rs[i][r] = 0.f;

#pragma unroll
    for (int j = 0; j < 4; j++) {
        const int n = nbase + wc * 64 + j * 16 + fr;
        const float ba = b_attn[n];
        const float vv = v[n];
#pragma unroll
        for (int i = 0; i < 8; i++)
#pragma unroll
            for (int r = 0; r < 4; r++) {
                float e  = acc[i][j][r] + ba;
                float ex = __expf(2.f * e);
                rs[i][r] += (1.f - 2.f / (ex + 1.f)) * vv;
            }
    }
#pragma unroll
    for (int off = 1; off < 16; off <<= 1)
#pragma unroll
        for (int i = 0; i < 8; i++)
#pragma unroll
            for (int r = 0; r < 4; r++) rs[i][r] += __shfl_xor(rs[i][r], off, 64);

    float v0 = 0.f, v1 = 0.f;
#pragma unroll
    for (int i = 0; i < 4; i++)
#pragma unroll
        for (int r = 0; r < 4; r++)
            if (fr == i * 4 + r) { v0 = rs[i][r]; v1 = rs[i + 4][r]; }

    const int plane = (swz & 3) * 4 + wc;
    const size_t pb = (size_t)plane * M_TOT + mbase + wr * 128 + g * 4 + (fr & 3);
    pscore16[pb + (fr >> 2) * 16]      = v0;
    pscore16[pb + (fr >> 2) * 16 + 64] = v1;
}

// ---------------- kernel 2: sum 16 partial planes + softmax over S ----------
__global__ __launch_bounds__(256) void k_softmax(const float* __restrict__ ps,
                                                 float* __restrict__ out) {
    const int b = blockIdx.x, t = threadIdx.x;
    __shared__ float red[8];
    float loc[8];
    float lmax = -1e30f;
#pragma unroll
    for (int i = 0; i < 8; i++) {
        const int s = t + i * 256;
        float sc = 0.f;
#pragma unroll
        for (int p = 0; p < 16; p++) sc += ps[(size_t)p * M_TOT + (size_t)b * SEQ + s];
        loc[i] = sc;
        lmax = fmaxf(lmax, sc);
    }
    for (int o = 32; o; o >>= 1) lmax = fmaxf(lmax, __shfl_xor(lmax, o, 64));
    if ((t & 63) == 0) red[t >> 6] = lmax;
    __syncthreads();
    const float bmax = fmaxf(fmaxf(red[0], red[1]), fmaxf(red[2], red[3]));
    float ev[8], lsum = 0.f;
#pragma unroll
    for (int i = 0; i < 8; i++) { ev[i] = expf(loc[i] - bmax); lsum += ev[i]; }
    for (int o = 32; o; o >>= 1) lsum += __shfl_xor(lsum, o, 64);
    __syncthreads();
    if ((t & 63) == 0) red[4 + (t >> 6)] = lsum;
    __syncthreads();
    const float inv = 1.f / (red[4] + red[5] + red[6] + red[7]);
#pragma unroll
    for (int i = 0; i < 8; i++)
        out[(size_t)BATCH * HID + (size_t)b * SEQ + t + i * 256] = ev[i] * inv;
}

// ---------------- kernel 3: partial context over S-chunks -------------------
__global__ __launch_bounds__(256) void k_pctx(const float* __restrict__ enc,
                                              const float* __restrict__ attn,
                                              float* __restrict__ pctx) {
    const int hc = blockIdx.x, scb = blockIdx.y, b = blockIdx.z;
    const int h = hc * 256 + threadIdx.x;
    const float* ap = attn + (size_t)b * SEQ + scb * 256;
    const float* ep = enc + ((size_t)b * SEQ + scb * 256) * HID + h;
    float a = 0.f;
#pragma unroll 4
    for (int s = 0; s < 256; s++) a += ap[s] * ep[(size_t)s * HID];
    pctx[((size_t)scb * BATCH + b) * HID + h] = a;
}

// ---------------- kernel 4: reduce partial contexts -------------------------
__global__ __launch_bounds__(256) void k_ctx(const float* __restrict__ pctx,
                                             float* __restrict__ out) {
    const int i = blockIdx.x * 256 + threadIdx.x;
    float a = 0.f;
#pragma unroll
    for (int p = 0; p < 8; p++) a += pctx[(size_t)p * BATCH * HID + i];
    out[i] = a;
}

extern "C" void kernel_launch(void* const* d_in, const int* in_sizes, int n_in,
                              void* d_out, int out_size, void* d_ws, size_t ws_size,
                              hipStream_t stream) {
    const float* hidden = (const float*)d_in[0];
    const float* enc    = (const float*)d_in[1];
    const float* W      = (const float*)d_in[2];
    const float* b_attn = (const float*)d_in[3];
    const float* v      = (const float*)d_in[4];
    float* out = (float*)d_out;

    char* ws = (char*)d_ws;
    unsigned short* w2 = (unsigned short*)ws;                 // 4 MB (dead after gemm)
    float* pscore16    = (float*)(ws + ((size_t)4 << 20));    // 4 MB
    float* pctx        = (float*)ws;                          // reuses w2 region post-gemm

    const int smemBytes = 65536 + 4096;
    hipFuncSetAttribute((const void*)k_gemm_scores,
                        hipFuncAttributeMaxDynamicSharedMemorySize, smemBytes);

    k_convW<<<dim3(512), dim3(256), 0, stream>>>(W, w2);
    k_gemm_scores<<<dim3(1024), dim3(512), smemBytes, stream>>>(
        enc, hidden, w2, b_attn, v, pscore16);
    k_softmax<<<dim3(BATCH), dim3(256), 0, stream>>>(pscore16, out);
    k_pctx<<<dim3(4, 8, BATCH), dim3(256), 0, stream>>>(enc, out + BATCH * HID, pctx);
    k_ctx<<<dim3(128), dim3(256), 0, stream>>>(pctx, out);
}

// Round 9
// 449.173 us; speedup vs baseline: 1.6766x; 1.6766x over previous
//
#include <hip/hip_runtime.h>
#include <hip/hip_bf16.h>

#define BATCH 32
#define SEQ   2048
#define HID   1024
#define M_TOT (BATCH*SEQ)
#define NG    32          // K groups of 32 (passes: xh*wh, xl*wh, xh*wl)

typedef __attribute__((ext_vector_type(8))) short          bf16x8;
typedef __attribute__((ext_vector_type(8))) unsigned short us8;
typedef __attribute__((ext_vector_type(4))) float          f32x4;
typedef __attribute__((ext_vector_type(4))) unsigned       u32x4;

__device__ __forceinline__ unsigned short f2bf_rn(float x) {
    unsigned u = __float_as_uint(x);
    return (unsigned short)((u + 0x7fffu + ((u >> 16) & 1u)) >> 16);
}
__device__ __forceinline__ float bf2f(unsigned short h) {
    return __uint_as_float(((unsigned)h) << 16);
}
// packed f32x2 -> bf16x2 (lo <- s0, hi <- s1), RTNE on gfx950
__device__ __forceinline__ unsigned cvt_pk_bf16(float s0, float s1) {
    unsigned r;
    asm("v_cvt_pk_bf16_f32 %0, %1, %2" : "=v"(r) : "v"(s0), "v"(s1));
    return r;
}

using as1_cv = const __attribute__((address_space(1))) void;
using as3_v  = __attribute__((address_space(3))) void;
__device__ __forceinline__ void gload16(const void* g, char* s) {
    __builtin_amdgcn_global_load_lds((as1_cv*)g, (as3_v*)s, 16, 0, 0);
}

#define FENCE() asm volatile("" ::: "memory")

// ---------------- kernel 0: W f32 -> bf16 hi/lo  w2 = [o][ wh(1024) | wl(1024) ] --
__global__ __launch_bounds__(256) void k_convW(const float* __restrict__ W,
                                               unsigned short* __restrict__ w2) {
    const int i8 = (blockIdx.x * 256 + threadIdx.x) * 8;
    const int o = i8 >> 10, h = i8 & 1023;
    float4 w0 = *(const float4*)(W + i8);
    float4 w1 = *(const float4*)(W + i8 + 4);
    float xs[8] = {w0.x, w0.y, w0.z, w0.w, w1.x, w1.y, w1.z, w1.w};
    us8 hv{}, lv{};
#pragma unroll
    for (int t = 0; t < 8; t++) {
        unsigned short xh = f2bf_rn(xs[t]);
        hv[t] = (unsigned short)xh;
        lv[t] = (unsigned short)f2bf_rn(xs[t] - bf2f(xh));
    }
    *(us8*)(w2 + (size_t)o * 2048 + h)        = hv;
    *(us8*)(w2 + (size_t)o * 2048 + 1024 + h) = lv;
}

// ------ kernel 1: fused (enc+hidden) @ W^T -> tanh -> dot(v) -> pscore8 ------
// A path REGISTER-ONLY with one-group-ahead prefetch:
//   body start: issue raw enc loads for G+1 into er[8] (32 VGPR)
//   body end:   convert er -> FH/FL frags (FH/FL of G are dead by then)
// Wave grid 4x2: wave = 64 rows x 128 cols; 4 conv sets/wave.
// Pass order xh*wh, xl*wh, xh*wl so bh[8] is read once and held.
// LDS (68 KB): B 2 slots x [wh|wl] x [256 rows][64 B] (XOR-swizzled,
// chunk c of row r at c ^ ((r>>1)&3)); hidL 4 KB f32 at 65536.
// ONE barrier/group with vmcnt(0) (all drained ops >= 1 group old -> free).
__global__ __launch_bounds__(512, 2) void k_gemm_scores(
    const float* __restrict__ enc,
    const float* __restrict__ hidden,
    const unsigned short* __restrict__ w2,
    const float* __restrict__ b_attn,
    const float* __restrict__ v,
    float* __restrict__ pscore8)
{
    extern __shared__ char smem[];
    float* hidL = (float*)(smem + 65536);

    const int tid  = threadIdx.x;
    const int lane = tid & 63, wid = tid >> 6;
    const int wr = wid >> 1, wc = wid & 1;           // 4 x 2 wave grid
    const int fr = lane & 15, g = lane >> 4;
    const int gsw = (g ^ ((fr >> 1) & 3)) * 16;      // swizzled chunk byte off

    const int bid  = blockIdx.x;
    const int swz  = (bid & 7) * 128 + (bid >> 3);   // XCD-chunk swizzle (bijective)
    const int mbase = (swz >> 2) * 256;
    const int nbase = (swz & 3) * 256;
    const int bidx  = mbase >> 11;                   // batch (BM=256 divides SEQ)

    // per-lane A base: enc row (mbase + wr*64 + fr), k offset g*8
    const float* encBase = enc + (size_t)(mbase + wr * 64 + fr) * HID + g * 8;

    // B gload mapping: dest linear (lane*16); source chunk pre-swizzled
    const int brow  = wid * 16 + (lane >> 2);
    const int bsx8  = ((lane & 3) ^ ((lane >> 3) & 3)) * 8;

    // hidden row -> LDS (1024 f32)
    *(float2*)(hidL + tid * 2) = *(const float2*)(hidden + (size_t)bidx * HID + tid * 2);

    f32x4 acc[4][8];
#pragma unroll
    for (int i = 0; i < 4; i++)
#pragma unroll
        for (int j = 0; j < 8; j++) acc[i][j] = (f32x4)0.f;

    bf16x8 FH[4], FL[4];
    float4 er[8];

    auto loadEncAll = [&](int Gn) {
#pragma unroll
        for (int s = 0; s < 4; s++) {
            const float* ep = encBase + (size_t)(s * 16) * HID + Gn * 32;
            er[s * 2]     = *(const float4*)ep;
            er[s * 2 + 1] = *(const float4*)(ep + 4);
        }
    };
    // convert er (raw enc) + hv (hidden) -> FH/FL, all 4 sets
    auto convAll = [&](const float* hv) {
#pragma unroll
        for (int s = 0; s < 4; s++) {
            float4 e0 = er[s * 2], e1 = er[s * 2 + 1];
            float x0 = e0.x + hv[0], x1 = e0.y + hv[1];
            float x2 = e0.z + hv[2], x3 = e0.w + hv[3];
            float x4 = e1.x + hv[4], x5 = e1.y + hv[5];
            float x6 = e1.z + hv[6], x7 = e1.w + hv[7];
            unsigned h01 = cvt_pk_bf16(x0, x1);
            unsigned h23 = cvt_pk_bf16(x2, x3);
            unsigned h45 = cvt_pk_bf16(x4, x5);
            unsigned h67 = cvt_pk_bf16(x6, x7);
            unsigned l01 = cvt_pk_bf16(x0 - __uint_as_float(h01 << 16),
                                       x1 - __uint_as_float(h01 & 0xffff0000u));
            unsigned l23 = cvt_pk_bf16(x2 - __uint_as_float(h23 << 16),
                                       x3 - __uint_as_float(h23 & 0xffff0000u));
            unsigned l45 = cvt_pk_bf16(x4 - __uint_as_float(h45 << 16),
                                       x5 - __uint_as_float(h45 & 0xffff0000u));
            unsigned l67 = cvt_pk_bf16(x6 - __uint_as_float(h67 << 16),
                                       x7 - __uint_as_float(h67 & 0xffff0000u));
            union { u32x4 u; bf16x8 b; } H, L;
            H.u[0] = h01; H.u[1] = h23; H.u[2] = h45; H.u[3] = h67;
            L.u[0] = l01; L.u[1] = l23; L.u[2] = l45; L.u[3] = l67;
            FH[s] = H.b;
            FL[s] = L.b;
        }
    };
    auto stageB = [&](int G2, int part) {   // part: 0=wh, 1=wl ; 2 gloads
        const unsigned short* s0 = w2 + (size_t)(nbase + brow) * 2048 + part * 1024 + G2 * 32 + bsx8;
        char* d0 = smem + (G2 & 1) * 32768 + part * 16384 + wid * 1024;
        gload16(s0, d0);
        gload16(s0 + (size_t)128 * 2048, d0 + 8192);
    };
    auto rdB = [&](int slot, int part, int j) -> bf16x8 {
        return *(const bf16x8*)(smem + slot * 32768 + part * 16384 +
                                (wc * 128 + j * 16 + fr) * 64 + gsw);
    };

    // ---- prologue: hidL; B(0) DMA; enc(0) -> er -> FH/FL ----
    stageB(0, 0); stageB(0, 1);
    loadEncAll(0);
    asm volatile("s_waitcnt lgkmcnt(0)" ::: "memory");   // hidL ds_write done
    __builtin_amdgcn_s_barrier(); FENCE();
    {
        float hv[8];
        *(float4*)&hv[0] = *(const float4*)(hidL + g * 8);
        *(float4*)&hv[4] = *(const float4*)(hidL + g * 8 + 4);
        convAll(hv);
    }

    for (int G = 0; G < NG; ++G) {
        const int slot = G & 1;
        // ---- group top: B(G) landed; everything outstanding is >=1 group old ----
        asm volatile("s_waitcnt vmcnt(0)" ::: "memory");
        __builtin_amdgcn_s_barrier(); FENCE();

        // issue next group's staging + raw A loads FIRST (hidden under MFMAs)
        if (G + 1 < NG) {
            stageB(G + 1, 0); stageB(G + 1, 1);          // 4 DMAs -> slot^1
            loadEncAll(G + 1);                           // 8 loads -> er
        }

        bf16x8 bh[8];
#pragma unroll
        for (int j = 0; j < 8; j++) bh[j] = rdB(slot, 0, j);

        // ---- pass 1: xh * wh ----
        __builtin_amdgcn_s_setprio(1);
#pragma unroll
        for (int j = 0; j < 8; j++)
#pragma unroll
            for (int i = 0; i < 4; i++)
                acc[i][j] = __builtin_amdgcn_mfma_f32_16x16x32_bf16(FH[i], bh[j], acc[i][j], 0, 0, 0);
        // ---- pass 2: xl * wh (FL dead after) ----
#pragma unroll
        for (int j = 0; j < 8; j++)
#pragma unroll
            for (int i = 0; i < 4; i++)
                acc[i][j] = __builtin_amdgcn_mfma_f32_16x16x32_bf16(FL[i], bh[j], acc[i][j], 0, 0, 0);
        __builtin_amdgcn_s_setprio(0);
        // ---- pass 3: xh * wl, bl streamed (FH dead after) ----
#pragma unroll
        for (int j = 0; j < 8; j++) {
            bf16x8 blj = rdB(slot, 1, j);
            __builtin_amdgcn_s_setprio(1);
#pragma unroll
            for (int i = 0; i < 4; i++)
                acc[i][j] = __builtin_amdgcn_mfma_f32_16x16x32_bf16(FH[i], blj, acc[i][j], 0, 0, 0);
            __builtin_amdgcn_s_setprio(0);
        }

        // ---- convert er -> FH/FL for G+1 (enc issued ~2500 cy ago) ----
        if (G + 1 < NG) {
            float hv[8];
            *(float4*)&hv[0] = *(const float4*)(hidL + (G + 1) * 32 + g * 8);
            *(float4*)&hv[4] = *(const float4*)(hidL + (G + 1) * 32 + g * 8 + 4);
            convAll(hv);
        }
    }

    // ---- epilogue: tanh(e+b)*v, reduce over cols, 1 plane per (nblk,wc) ----
    float rs[4][4];
#pragma unroll
    for (int i = 0; i < 4; i++)
#pragma unroll
        for (int r = 0; r < 4; r++) rs[i][r] = 0.f;

#pragma unroll
    for (int j = 0; j < 8; j++) {
        const int n = nbase + wc * 128 + j * 16 + fr;
        const float ba = b_attn[n];
        const float vv = v[n];
#pragma unroll
        for (int i = 0; i < 4; i++)
#pragma unroll
            for (int r = 0; r < 4; r++) {
                float e  = acc[i][j][r] + ba;
                float ex = __expf(2.f * e);
                rs[i][r] += (1.f - 2.f / (ex + 1.f)) * vv;
            }
    }
#pragma unroll
    for (int off = 1; off < 16; off <<= 1)
#pragma unroll
        for (int i = 0; i < 4; i++)
#pragma unroll
            for (int r = 0; r < 4; r++) rs[i][r] += __shfl_xor(rs[i][r], off, 64);

    float v0 = 0.f;
#pragma unroll
    for (int i = 0; i < 4; i++)
#pragma unroll
        for (int r = 0; r < 4; r++)
            if (fr == i * 4 + r) v0 = rs[i][r];

    const int plane = (swz & 3) * 2 + wc;
    pscore8[(size_t)plane * M_TOT + mbase + wr * 64 +
            (fr >> 2) * 16 + g * 4 + (fr & 3)] = v0;
}

// ---------------- kernel 2: sum 8 partial planes + softmax over S ----------
__global__ __launch_bounds__(256) void k_softmax(const float* __restrict__ ps,
                                                 float* __restrict__ out) {
    const int b = blockIdx.x, t = threadIdx.x;
    __shared__ float red[8];
    float loc[8];
    float lmax = -1e30f;
#pragma unroll
    for (int i = 0; i < 8; i++) {
        const int s = t + i * 256;
        float sc = 0.f;
#pragma unroll
        for (int p = 0; p < 8; p++) sc += ps[(size_t)p * M_TOT + (size_t)b * SEQ + s];
        loc[i] = sc;
        lmax = fmaxf(lmax, sc);
    }
    for (int o = 32; o; o >>= 1) lmax = fmaxf(lmax, __shfl_xor(lmax, o, 64));
    if ((t & 63) == 0) red[t >> 6] = lmax;
    __syncthreads();
    const float bmax = fmaxf(fmaxf(red[0], red[1]), fmaxf(red[2], red[3]));
    float ev[8], lsum = 0.f;
#pragma unroll
    for (int i = 0; i < 8; i++) { ev[i] = expf(loc[i] - bmax); lsum += ev[i]; }
    for (int o = 32; o; o >>= 1) lsum += __shfl_xor(lsum, o, 64);
    __syncthreads();
    if ((t & 63) == 0) red[4 + (t >> 6)] = lsum;
    __syncthreads();
    const float inv = 1.f / (red[4] + red[5] + red[6] + red[7]);
#pragma unroll
    for (int i = 0; i < 8; i++)
        out[(size_t)BATCH * HID + (size_t)b * SEQ + t + i * 256] = ev[i] * inv;
}

// ---------------- kernel 3: partial context over S-chunks -------------------
__global__ __launch_bounds__(256) void k_pctx(const float* __restrict__ enc,
                                              const float* __restrict__ attn,
                                              float* __restrict__ pctx) {
    const int hc = blockIdx.x, scb = blockIdx.y, b = blockIdx.z;
    const int h = hc * 256 + threadIdx.x;
    const float* ap = attn + (size_t)b * SEQ + scb * 256;
    const float* ep = enc + ((size_t)b * SEQ + scb * 256) * HID + h;
    float a = 0.f;
#pragma unroll 4
    for (int s = 0; s < 256; s++) a += ap[s] * ep[(size_t)s * HID];
    pctx[((size_t)scb * BATCH + b) * HID + h] = a;
}

// ---------------- kernel 4: reduce partial contexts -------------------------
__global__ __launch_bounds__(256) void k_ctx(const float* __restrict__ pctx,
                                             float* __restrict__ out) {
    const int i = blockIdx.x * 256 + threadIdx.x;
    float a = 0.f;
#pragma unroll
    for (int p = 0; p < 8; p++) a += pctx[(size_t)p * BATCH * HID + i];
    out[i] = a;
}

extern "C" void kernel_launch(void* const* d_in, const int* in_sizes, int n_in,
                              void* d_out, int out_size, void* d_ws, size_t ws_size,
                              hipStream_t stream) {
    const float* hidden = (const float*)d_in[0];
    const float* enc    = (const float*)d_in[1];
    const float* W      = (const float*)d_in[2];
    const float* b_attn = (const float*)d_in[3];
    const float* v      = (const float*)d_in[4];
    float* out = (float*)d_out;

    char* ws = (char*)d_ws;
    unsigned short* w2 = (unsigned short*)ws;                 // 4 MB (dead after gemm)
    float* pscore8     = (float*)(ws + ((size_t)4 << 20));    // 2 MB
    float* pctx        = (float*)ws;                          // reuses w2 region post-gemm

    const int smemBytes = 65536 + 4096;
    hipFuncSetAttribute((const void*)k_gemm_scores,
                        hipFuncAttributeMaxDynamicSharedMemorySize, smemBytes);

    k_convW<<<dim3(512), dim3(256), 0, stream>>>(W, w2);
    k_gemm_scores<<<dim3(1024), dim3(512), smemBytes, stream>>>(
        enc, hidden, w2, b_attn, v, pscore8);
    k_softmax<<<dim3(BATCH), dim3(256), 0, stream>>>(pscore8, out);
    k_pctx<<<dim3(4, 8, BATCH), dim3(256), 0, stream>>>(enc, out + BATCH * HID, pctx);
    k_ctx<<<dim3(128), dim3(256), 0, stream>>>(pctx, out);
}